// Round 4
// baseline (797.277 us; speedup 1.0000x reference)
//
#include <hip/hip_runtime.h>
#include <stdint.h>

// Problem constants
constexpr int B_ = 8, N_ = 4096, E_ = 2048, C_ = 128;
constexpr int KT  = 32;    // K per MFMA step
constexpr int NWK = 4;     // K-split across the 4 waves of a block
constexpr int NJ  = C_ / 16;  // 8 col-tiles
constexpr int LRF = 132;   // reduction LDS row stride (floats)

typedef short bf16x8 __attribute__((ext_vector_type(8)));
typedef float f32x4  __attribute__((ext_vector_type(4)));

__device__ inline uint16_t bf16_rne(float f) {
    uint32_t u = __builtin_bit_cast(uint32_t, f);
    return (uint16_t)((u + 0x7FFFu + ((u >> 16) & 1u)) >> 16);
}

__device__ __attribute__((always_inline)) inline void glds16(const void* g, void* l) {
    __builtin_amdgcn_global_load_lds(
        (const __attribute__((address_space(1))) uint32_t*)g,
        (__attribute__((address_space(3))) uint32_t*)l, 16, 0, 0);
}

constexpr size_t HT_E  = (size_t)B_ * (N_ / 32) * E_;  // 2M dwords = 8 MB
constexpr size_t WT_E  = (size_t)C_ * C_;              // 16384 bf16
constexpr size_t EBF_E = (size_t)B_ * C_ * E_;         // 2M bf16 = 4 MB
constexpr size_t RS_E  = (size_t)B_ * E_;              // 16K floats
constexpr size_t RD_E  = (size_t)B_ * N_;              // 32K floats

// ---------------------------------------------------------------------------
// pack: H (fp32 0/1) -> HT[b][n/32][e], bit i of word = H[b][32*(n/32)+i][e].
// ---------------------------------------------------------------------------
__global__ void pack_kernel(const float* __restrict__ H, uint32_t* __restrict__ HT) {
    const int t  = threadIdx.x;
    const int eg = blockIdx.x & 7;
    const int ng = (blockIdx.x >> 3) & 127;
    const int b  = blockIdx.x >> 10;
    const int e  = eg * 256 + t;
    const float* hp = H + ((size_t)b * N_ + ng * 32) * E_ + e;
    uint32_t w = 0;
#pragma unroll
    for (int i = 0; i < 32; ++i) w |= (hp[(size_t)i * E_] > 0.5f) ? (1u << i) : 0u;
    HT[((size_t)b * (N_ / 32) + ng) * E_ + e] = w;
}

// ---------------------------------------------------------------------------
// prep: rd_n (ballot over HT rows), rs_e (popcount over HT cols), WTb.
// ---------------------------------------------------------------------------
__global__ void prep_kernel(const float* __restrict__ W, const uint32_t* __restrict__ HT,
                            uint16_t* __restrict__ WTb, float* __restrict__ rs_e,
                            float* __restrict__ rd_n) {
    const int blk = blockIdx.x, t = threadIdx.x;
    if (blk < 256) {
        const int wave = t >> 6, lane = t & 63;
        const int wid  = blk * 4 + wave;          // 0..1023 = (b, ng)
        const int b = wid >> 7, ng = wid & 127;
        const uint32_t* p = HT + ((size_t)b * (N_ / 32) + ng) * E_;
        int cnt = 0;
#pragma unroll 1
        for (int c8 = 0; c8 < E_ / 64; ++c8) {
            const uint32_t w = p[c8 * 64 + lane];
#pragma unroll
            for (int i = 0; i < 32; ++i) {
                unsigned long long m = __ballot((w >> i) & 1u);
                if (lane == i) cnt += __popcll(m);
            }
        }
        if (lane < 32)
            rd_n[(size_t)b * N_ + ng * 32 + lane] = (cnt > 0) ? 1.f / (float)cnt : 0.f;
    } else if (blk < 320) {
        const int i = (blk - 256) * 256 + t;      // 0..16383 = (b, e)
        const int b = i >> 11, e = i & 2047;
        const uint32_t* p = HT + (size_t)b * (N_ / 32) * E_ + e;
        int s = 0;
#pragma unroll 1
        for (int ng = 0; ng < N_ / 32; ++ng) s += __popc(p[(size_t)ng * E_]);
        rs_e[i] = (s > 0) ? 1.f / (float)s : 0.f;
    } else {
        const int i = (blk - 320) * 256 + t;      // 0..16383 = c*128+k
        const int c = i >> 7, k = i & 127;
        WTb[i] = bf16_rne(W[k * C_ + c]);
    }
}

// ---------------------------------------------------------------------------
// MFMA GEMM body (round-3 structure), parameterized by MT (16-row groups NG)
// and REP (idempotent repeat for rocprof surfacing). Per-wave-private LDS B
// double-buffers via global_load_lds; zero main-loop barriers; counted vmcnt.
// ---------------------------------------------------------------------------

#define LOADA(S, k0_) do {                                                            \
    if constexpr (MODE == 0) {                                                        \
        _Pragma("unroll")                                                             \
        for (int g = 0; g < NG; ++g) {                                                \
            const float* ap = Ax + ((size_t)batch * N_ + m0 + g * 16 + l15) * C_ + (k0_) + quad * 8; \
            const float4 f0 = *(const float4*)ap;                                     \
            const float4 f1 = *(const float4*)(ap + 4);                               \
            af##S[g*8+0]=f0.x; af##S[g*8+1]=f0.y; af##S[g*8+2]=f0.z; af##S[g*8+3]=f0.w; \
            af##S[g*8+4]=f1.x; af##S[g*8+5]=f1.y; af##S[g*8+6]=f1.z; af##S[g*8+7]=f1.w; \
        }                                                                             \
    } else if constexpr (MODE == 1) {                                                 \
        const uint32_t* p = Hp + (size_t)((k0_) >> 5) * E_ + m0 + l15;                \
        _Pragma("unroll")                                                             \
        for (int g = 0; g < NG; ++g) aw##S[g] = p[g * 16];                            \
    } else {                                                                          \
        const uint32_t* p = Hp + (size_t)(m0 >> 5) * E_ + (k0_) + quad * 8;           \
        _Pragma("unroll")                                                             \
        for (int r = 0; r < NG / 2; ++r) {                                            \
            axl##S[r] = *(const uint4*)(p + r * E_);                                  \
            axh##S[r] = *(const uint4*)(p + r * E_ + 4);                              \
        }                                                                             \
    } } while (0)

#define MKFRAGS(S, A)                                                                 \
    bf16x8 A[NG];                                                                     \
    do {                                                                              \
    if constexpr (MODE == 0) {                                                        \
        _Pragma("unroll")                                                             \
        for (int g = 0; g < NG; ++g)                                                  \
            { _Pragma("unroll")                                                       \
              for (int jj = 0; jj < 8; ++jj) A[g][jj] = (short)bf16_rne(af##S[g*8+jj]); } \
    } else if constexpr (MODE == 1) {                                                 \
        _Pragma("unroll")                                                             \
        for (int g = 0; g < NG; ++g) {                                                \
            const uint32_t w = aw##S[g];                                              \
            _Pragma("unroll")                                                         \
            for (int jj = 0; jj < 8; ++jj)                                            \
                A[g][jj] = (short)(((w >> (quad * 8 + jj)) & 1u) ? 0x3F80 : 0);       \
        }                                                                             \
    } else {                                                                          \
        _Pragma("unroll")                                                             \
        for (int g = 0; g < NG; ++g) {                                                \
            const int row = g >> 1, bit = (g & 1) * 16 + l15;                         \
            const uint32_t u[8] = {axl##S[row].x, axl##S[row].y, axl##S[row].z, axl##S[row].w, \
                                   axh##S[row].x, axh##S[row].y, axh##S[row].z, axh##S[row].w}; \
            _Pragma("unroll")                                                         \
            for (int jj = 0; jj < 8; ++jj)                                            \
                A[g][jj] = (short)(((u[jj] >> bit) & 1u) ? 0x3F80 : 0);               \
        }                                                                             \
    } } while (0)

template <int MODE, int MTt, int REP>
__device__ __attribute__((always_inline))
void gemm_body(const float* __restrict__ Ax, const uint32_t* __restrict__ HT,
               const uint16_t* __restrict__ Btb, const float* __restrict__ bias,
               const float* __restrict__ rcp, uint16_t* __restrict__ outT,
               float* __restrict__ outF) {
    constexpr int K   = (MODE == 0) ? C_ : (MODE == 1) ? N_ : E_;
    constexpr int KW  = K / NWK;
    constexpr int SW  = KW / KT;
    constexpr int OLD = (MODE == 0) ? N_ : E_;
    constexpr int RL  = (MODE == 1) ? E_ : N_;
    constexpr int NG  = MTt / 16;                 // 16-row groups per wave
    constexpr int VMC = 8 + ((MODE == 0) ? 2 * NG : NG);  // per-step vmem issues
    constexpr size_t RBYTES = (size_t)2 * MTt * LRF * 4;
    constexpr size_t SMEMB  = (RBYTES > 65536) ? RBYTES : 65536;

    __shared__ __align__(16) uint8_t smem[SMEMB];  // B-tiles (main) / R (reduction)

    const int t = threadIdx.x, wave = t >> 6, lane = t & 63;
    const int l15 = lane & 15, quad = lane >> 4;
    const int batch = blockIdx.x & 7;             // batch -> XCD: panel stays in one L2
    const int m0 = (blockIdx.x >> 3) * MTt;
    const int kwv = wave * KW;

    const uint16_t* Bp = Btb + (MODE == 0 ? (size_t)0 : (size_t)batch * C_ * K);
    const uint32_t* Hp = HT + (size_t)batch * (N_ / 32) * E_;
    float* R = (float*)smem;
    uint8_t* myB = smem + wave * 16384;

    f32x4 acc[NG * 8];
    float    af0[NG * 8], af1[NG * 8];
    uint32_t aw0[NG], aw1[NG];
    uint4    axl0[NG / 2], axh0[NG / 2], axl1[NG / 2], axh1[NG / 2];
    bf16x8   bfr[NJ];

    auto issueB = [&](int k0, int p) __attribute__((always_inline)) {
        uint8_t* dst = myB + p * 8192;
#pragma unroll
        for (int j = 0; j < NJ; ++j)
            glds16(&Bp[(size_t)(j * 16 + l15) * K + k0 + quad * 8], dst + j * 1024);
    };
    auto readB = [&](int p) __attribute__((always_inline)) {
        const uint8_t* src = myB + p * 8192 + lane * 16;
#pragma unroll
        for (int j = 0; j < NJ; ++j)
            bfr[j] = *(const bf16x8*)(src + j * 1024);
    };
    auto mfma_all = [&](const bf16x8 (&A)[NG]) __attribute__((always_inline)) {
#pragma unroll
        for (int j = 0; j < NJ; ++j)
#pragma unroll
            for (int g = 0; g < NG; ++g)
                acc[g * 8 + j] = __builtin_amdgcn_mfma_f32_16x16x32_bf16(A[g], bfr[j], acc[g * 8 + j], 0, 0, 0);
    };
    auto wait_vm = [&](bool last) __attribute__((always_inline)) {
        if (last) { asm volatile("s_waitcnt vmcnt(0)" ::: "memory"); return; }
        if constexpr (VMC == 10)      asm volatile("s_waitcnt vmcnt(10)" ::: "memory");
        else if constexpr (VMC == 12) asm volatile("s_waitcnt vmcnt(12)" ::: "memory");
        else                          asm volatile("s_waitcnt vmcnt(16)" ::: "memory");
    };
    auto stR = [&](int base) __attribute__((always_inline)) {
#pragma unroll
        for (int g = 0; g < NG; ++g)
#pragma unroll
            for (int j = 0; j < NJ; ++j)
#pragma unroll
                for (int r = 0; r < 4; ++r)
                    R[base + (g * 16 + quad * 4 + r) * LRF + j * 16 + l15] = acc[g * 8 + j][r];
    };
    auto ldR = [&](int base) __attribute__((always_inline)) {
#pragma unroll
        for (int g = 0; g < NG; ++g)
#pragma unroll
            for (int j = 0; j < NJ; ++j)
#pragma unroll
                for (int r = 0; r < 4; ++r)
                    acc[g * 8 + j][r] += R[base + (g * 16 + quad * 4 + r) * LRF + j * 16 + l15];
    };

#pragma unroll 1
    for (int rep = 0; rep < REP; ++rep) {
        asm volatile("" ::: "memory");            // block cross-rep CSE

#pragma unroll
        for (int i = 0; i < NG * 8; ++i) acc[i] = (f32x4){0.f, 0.f, 0.f, 0.f};

        // prologue: (A,B)(0) then (A,B)(1)
        LOADA(0, kwv);
        issueB(kwv, 0);
        if constexpr (SW > 1) { LOADA(1, kwv + KT); issueB(kwv + KT, 1); }

#pragma unroll 1
        for (int s = 0; s < SW; s += 2) {
            {   // even step: set0 / buf0
                wait_vm(SW == 1 || s == SW - 1);
                readB(0);
                MKFRAGS(0, Aa);
                asm volatile("s_waitcnt lgkmcnt(0)" ::: "memory");
                if (s + 2 < SW) { LOADA(0, kwv + (s + 2) * KT); issueB(kwv + (s + 2) * KT, 0); }
                mfma_all(Aa);
            }
            if (s + 1 < SW) {  // odd step: set1 / buf1
                wait_vm(s + 1 == SW - 1);
                readB(1);
                MKFRAGS(1, Ab);
                asm volatile("s_waitcnt lgkmcnt(0)" ::: "memory");
                if (s + 3 < SW) { LOADA(1, kwv + (s + 3) * KT); issueB(kwv + (s + 3) * KT, 1); }
                mfma_all(Ab);
            }
        }

        // ---- cross-wave K reduction (R aliases B-tiles -> barrier first) ----
        __syncthreads();
        if (wave == 1) stR(0);
        if (wave == 3) stR(MTt * LRF);
        __syncthreads();
        if (wave == 0) ldR(0);
        if (wave == 2) ldR(MTt * LRF);
        __syncthreads();
        if (wave == 2) stR(0);
        __syncthreads();

        if (wave == 0) {
            ldR(0);
            float mul[NG][4];
            if constexpr (MODE != 0) {
#pragma unroll
                for (int g = 0; g < NG; ++g) {
                    const float4 rv = *(const float4*)&rcp[(size_t)batch * RL + m0 + g * 16 + quad * 4];
                    mul[g][0] = rv.x; mul[g][1] = rv.y; mul[g][2] = rv.z; mul[g][3] = rv.w;
                }
            }
#pragma unroll
            for (int g = 0; g < NG; ++g) {
                const int row = m0 + g * 16 + quad * 4;
                if constexpr (MODE == 2) {
                    float* op = outF + ((size_t)batch * N_ + row) * C_;
#pragma unroll
                    for (int j = 0; j < NJ; ++j) {
                        int c = j * 16 + l15;
#pragma unroll
                        for (int r = 0; r < 4; ++r) op[(size_t)r * C_ + c] = acc[g * 8 + j][r] * mul[g][r];
                    }
                } else {
#pragma unroll
                    for (int j = 0; j < NJ; ++j) {
                        int c = j * 16 + l15;
                        float v0, v1, v2, v3;
                        if constexpr (MODE == 0) {
                            float bb = bias[c];
                            v0 = acc[g * 8 + j][0] + bb; v1 = acc[g * 8 + j][1] + bb;
                            v2 = acc[g * 8 + j][2] + bb; v3 = acc[g * 8 + j][3] + bb;
                        } else {
                            v0 = acc[g * 8 + j][0] * mul[g][0]; v1 = acc[g * 8 + j][1] * mul[g][1];
                            v2 = acc[g * 8 + j][2] * mul[g][2]; v3 = acc[g * 8 + j][3] * mul[g][3];
                        }
                        uint32_t q0 = (uint32_t)bf16_rne(v0) | ((uint32_t)bf16_rne(v1) << 16);
                        uint32_t q1 = (uint32_t)bf16_rne(v2) | ((uint32_t)bf16_rne(v3) << 16);
                        uint16_t* op = outT + ((size_t)batch * C_ + c) * OLD + row;
                        *(uint2*)op = make_uint2(q0, q1);
                    }
                }
            }
        }
        __syncthreads();   // protect R / B-tiles before next rep
    }
}

// Named wrappers -> attributable rocprof rows
__global__ __launch_bounds__(256, 2)
void fc_k(const float* __restrict__ Ax, const uint16_t* __restrict__ Btb,
          const float* __restrict__ bias, uint16_t* __restrict__ outT) {
    gemm_body<0, 64, 1>(Ax, nullptr, Btb, bias, nullptr, outT, nullptr);
}
__global__ __launch_bounds__(256, 2)
void v2e_k(const uint32_t* __restrict__ HT, const uint16_t* __restrict__ Btb,
           const float* __restrict__ rcp, uint16_t* __restrict__ outT) {
    gemm_body<1, 32, 6>(nullptr, HT, Btb, nullptr, rcp, outT, nullptr);  // MT=32, REP=6 (diag)
}
__global__ __launch_bounds__(256, 2)
void e2v_k(const uint32_t* __restrict__ HT, const uint16_t* __restrict__ Btb,
           const float* __restrict__ rcp, float* __restrict__ outF) {
    gemm_body<2, 64, 1>(nullptr, HT, Btb, nullptr, rcp, nullptr, outF);
}

// ---------------------------------------------------------------------------
extern "C" void kernel_launch(void* const* d_in, const int* in_sizes, int n_in,
                              void* d_out, int out_size, void* d_ws, size_t ws_size,
                              hipStream_t stream) {
    const float* x    = (const float*)d_in[0];   // [8,4096,128]
    const float* H    = (const float*)d_in[1];   // [8,4096,2048]
    const float* W    = (const float*)d_in[2];   // [128,128]
    const float* bias = (const float*)d_in[3];   // [128]
    float* out = (float*)d_out;                  // [8,4096,128]

    // ws (~12.3 MB): HT 8MB | WTb 32KB | ebfT 4MB | rs_e 64KB | rd_n 128KB
    uint32_t* HT   = (uint32_t*)d_ws;
    uint16_t* WTb  = (uint16_t*)(HT + HT_E);
    uint16_t* ebfT = WTb + WT_E;
    float*    rs_e = (float*)(ebfT + EBF_E);
    float*    rd_n = rs_e + RS_E;
    uint16_t* xwbT = (uint16_t*)d_out;           // d_out is dead scratch until e2v

    pack_kernel<<<dim3(8192), dim3(256), 0, stream>>>(H, HT);
    prep_kernel<<<dim3(384), dim3(256), 0, stream>>>(W, HT, WTb, rs_e, rd_n);
    fc_k <<<dim3(8 * (N_ / 64)), dim3(256), 0, stream>>>(x, WTb, bias, xwbT);
    v2e_k<<<dim3(8 * (E_ / 32)), dim3(256), 0, stream>>>(HT, xwbT, rs_e, ebfT);
    e2v_k<<<dim3(8 * (N_ / 64)), dim3(256), 0, stream>>>(HT, ebfT, rd_n, out);
}

// Round 6
// 497.378 us; speedup vs baseline: 1.6030x; 1.6030x over previous
//
#include <hip/hip_runtime.h>
#include <stdint.h>

// Problem constants
constexpr int B_ = 8, N_ = 4096, E_ = 2048, C_ = 128;
constexpr int KT = 32;     // K per MFMA step
constexpr int MT = 64;     // M rows per block (4 x 16-row groups)
constexpr int NJW = 2;     // col-tiles per wave (8 tiles / 4 waves) -- N-split

typedef short bf16x8 __attribute__((ext_vector_type(8)));
typedef float f32x4  __attribute__((ext_vector_type(4)));

__device__ inline uint16_t bf16_rne(float f) {
    uint32_t u = __builtin_bit_cast(uint32_t, f);
    return (uint16_t)((u + 0x7FFFu + ((u >> 16) & 1u)) >> 16);
}

constexpr size_t HT_E  = (size_t)B_ * (N_ / 32) * E_;  // 2M dwords = 8 MB
constexpr size_t WT_E  = (size_t)C_ * C_;              // 16384 bf16
constexpr size_t EBF_E = (size_t)B_ * C_ * E_;         // 2M bf16 = 4 MB
constexpr size_t RS_E  = (size_t)B_ * E_;              // 16K floats
constexpr size_t RD_E  = (size_t)B_ * N_;              // 32K floats

// ---------------------------------------------------------------------------
// pack: H (fp32 0/1) -> HT[b][n/32][e], bit i of word = H[b][32*(n/32)+i][e].
// ---------------------------------------------------------------------------
__global__ void pack_kernel(const float* __restrict__ H, uint32_t* __restrict__ HT) {
    const int t  = threadIdx.x;
    const int eg = blockIdx.x & 7;
    const int ng = (blockIdx.x >> 3) & 127;
    const int b  = blockIdx.x >> 10;
    const int e  = eg * 256 + t;
    const float* hp = H + ((size_t)b * N_ + ng * 32) * E_ + e;
    uint32_t w = 0;
#pragma unroll
    for (int i = 0; i < 32; ++i) w |= (hp[(size_t)i * E_] > 0.5f) ? (1u << i) : 0u;
    HT[((size_t)b * (N_ / 32) + ng) * E_ + e] = w;
}

// ---------------------------------------------------------------------------
// prep: rd_n (ballot over HT rows), rs_e (popcount over HT cols), WTb.
// ---------------------------------------------------------------------------
__global__ void prep_kernel(const float* __restrict__ W, const uint32_t* __restrict__ HT,
                            uint16_t* __restrict__ WTb, float* __restrict__ rs_e,
                            float* __restrict__ rd_n) {
    const int blk = blockIdx.x, t = threadIdx.x;
    if (blk < 256) {
        const int wave = t >> 6, lane = t & 63;
        const int wid  = blk * 4 + wave;          // 0..1023 = (b, ng)
        const int b = wid >> 7, ng = wid & 127;
        const uint32_t* p = HT + ((size_t)b * (N_ / 32) + ng) * E_;
        int cnt = 0;
#pragma unroll 1
        for (int c8 = 0; c8 < E_ / 64; ++c8) {
            const uint32_t w = p[c8 * 64 + lane];
#pragma unroll
            for (int i = 0; i < 32; ++i) {
                unsigned long long m = __ballot((w >> i) & 1u);
                if (lane == i) cnt += __popcll(m);
            }
        }
        if (lane < 32)
            rd_n[(size_t)b * N_ + ng * 32 + lane] = (cnt > 0) ? 1.f / (float)cnt : 0.f;
    } else if (blk < 320) {
        const int i = (blk - 256) * 256 + t;      // 0..16383 = (b, e)
        const int b = i >> 11, e = i & 2047;
        const uint32_t* p = HT + (size_t)b * (N_ / 32) * E_ + e;
        int s = 0;
#pragma unroll 1
        for (int ng = 0; ng < N_ / 32; ++ng) s += __popc(p[(size_t)ng * E_]);
        rs_e[i] = (s > 0) ? 1.f / (float)s : 0.f;
    } else {
        const int i = (blk - 320) * 256 + t;      // 0..16383 = c*128+k
        const int c = i >> 7, k = i & 127;
        WTb[i] = bf16_rne(W[k * C_ + c]);
    }
}

// ---------------------------------------------------------------------------
// N-SPLIT MFMA GEMM, all-register pipeline (round-6). Each wave owns 2 of 8
// col-tiles and sweeps the FULL K -> disjoint output slices, zero barriers,
// no reduction. B is held in a 4-deep NAMED-REGISTER pipeline (bq0..bq3, 8
// VGPRs/step) instead of LDS+global_load_lds: all loads are register-
// destination, so the COMPILER's scoreboard inserts provably-correct counted
// waitcnts (round-5's manual vmcnt counting raced when spill traffic shifted
// the retirement window). Program order (consume step s, then issue loads
// for s+4) keeps a 3-step prefetch lead.
//  MODE 0 (fc) : A = x fp32,    B = WTb,  out bf16 C^T xwbT (+bias)
//  MODE 1 (v2e): A = H^T bits,  B = xwbT, out bf16 C^T ebfT (x rs_e)
//  MODE 2 (e2v): A = H bits,    B = ebfT, out fp32 row-major (x rd_n)
// ---------------------------------------------------------------------------

#define LOADA(S, k0_) do {                                                            \
    if constexpr (MODE == 0) {                                                        \
        _Pragma("unroll")                                                             \
        for (int g = 0; g < NG; ++g) {                                                \
            const float* ap = Ax + ((size_t)batch * N_ + m0 + g * 16 + l15) * C_ + (k0_) + quad * 8; \
            const float4 f0 = *(const float4*)ap;                                     \
            const float4 f1 = *(const float4*)(ap + 4);                               \
            af##S[g*8+0]=f0.x; af##S[g*8+1]=f0.y; af##S[g*8+2]=f0.z; af##S[g*8+3]=f0.w; \
            af##S[g*8+4]=f1.x; af##S[g*8+5]=f1.y; af##S[g*8+6]=f1.z; af##S[g*8+7]=f1.w; \
        }                                                                             \
    } else if constexpr (MODE == 1) {                                                 \
        const uint32_t* p = Hp + (size_t)((k0_) >> 5) * E_ + m0 + l15;                \
        _Pragma("unroll")                                                             \
        for (int g = 0; g < NG; ++g) aw##S[g] = p[g * 16];                            \
    } else {                                                                          \
        const uint32_t* p = Hp + (size_t)(m0 >> 5) * E_ + (k0_) + quad * 8;           \
        _Pragma("unroll")                                                             \
        for (int r = 0; r < NG / 2; ++r) {                                            \
            axl##S[r] = *(const uint4*)(p + r * E_);                                  \
            axh##S[r] = *(const uint4*)(p + r * E_ + 4);                              \
        }                                                                             \
    } } while (0)

#define LOADB(S, k0_) do {                                                            \
    _Pragma("unroll")                                                                 \
    for (int j2 = 0; j2 < NJW; ++j2)                                                  \
        bq##S[j2] = *(const bf16x8*)&Bp[(size_t)((jw + j2) * 16 + l15) * K + (k0_) + quad * 8]; \
    } while (0)

#define MKFRAGS(S, A)                                                                 \
    bf16x8 A[NG];                                                                     \
    do {                                                                              \
    if constexpr (MODE == 0) {                                                        \
        _Pragma("unroll")                                                             \
        for (int g = 0; g < NG; ++g)                                                  \
            { _Pragma("unroll")                                                       \
              for (int jj = 0; jj < 8; ++jj) A[g][jj] = (short)bf16_rne(af##S[g*8+jj]); } \
    } else if constexpr (MODE == 1) {                                                 \
        _Pragma("unroll")                                                             \
        for (int g = 0; g < NG; ++g) {                                                \
            const uint32_t w = aw##S[g];                                              \
            _Pragma("unroll")                                                         \
            for (int jj = 0; jj < 8; ++jj)                                            \
                A[g][jj] = (short)(((w >> (quad * 8 + jj)) & 1u) ? 0x3F80 : 0);       \
        }                                                                             \
    } else {                                                                          \
        _Pragma("unroll")                                                             \
        for (int g = 0; g < NG; ++g) {                                                \
            const int row = g >> 1, bit = (g & 1) * 16 + l15;                         \
            const uint32_t u[8] = {axl##S[row].x, axl##S[row].y, axl##S[row].z, axl##S[row].w, \
                                   axh##S[row].x, axh##S[row].y, axh##S[row].z, axh##S[row].w}; \
            _Pragma("unroll")                                                         \
            for (int jj = 0; jj < 8; ++jj)                                            \
                A[g][jj] = (short)(((u[jj] >> bit) & 1u) ? 0x3F80 : 0);               \
        }                                                                             \
    } } while (0)

template <int MODE, int REP>
__device__ __attribute__((always_inline))
void gemm_body(const float* __restrict__ Ax, const uint32_t* __restrict__ HT,
               const uint16_t* __restrict__ Btb, const float* __restrict__ bias,
               const float* __restrict__ rcp, uint16_t* __restrict__ outT,
               float* __restrict__ outF) {
    constexpr int K   = (MODE == 0) ? C_ : (MODE == 1) ? N_ : E_;
    constexpr int SW  = K / KT;                   // 4 / 128 / 64 steps, full K per wave
    constexpr int OLD = (MODE == 0) ? N_ : E_;
    constexpr int RL  = (MODE == 1) ? E_ : N_;
    constexpr int NG  = MT / 16;                  // 4 m-groups per wave
    static_assert(SW >= 4 && SW % 4 == 0, "pipeline needs SW multiple of 4");

    const int t = threadIdx.x, wave = t >> 6, lane = t & 63;
    const int l15 = lane & 15, quad = lane >> 4;
    const int batch = blockIdx.x & 7;             // batch -> XCD: panel stays in one L2
    const int m0 = (blockIdx.x >> 3) * MT;
    const int jw = wave * NJW;                    // first owned col-tile

    const uint16_t* Bp = Btb + (MODE == 0 ? (size_t)0 : (size_t)batch * C_ * K);
    const uint32_t* Hp = HT + (size_t)batch * (N_ / 32) * E_;

    f32x4 acc[NG * NJW];
    // 4-deep named register pipeline (rule #20: static names, no runtime idx)
    float    af0[NG * 8], af1[NG * 8], af2[NG * 8], af3[NG * 8];
    uint32_t aw0[NG], aw1[NG], aw2[NG], aw3[NG];
    uint4    axl0[NG / 2], axh0[NG / 2], axl1[NG / 2], axh1[NG / 2];
    uint4    axl2[NG / 2], axh2[NG / 2], axl3[NG / 2], axh3[NG / 2];
    bf16x8   bq0[NJW], bq1[NJW], bq2[NJW], bq3[NJW];

    auto mfma_all = [&](const bf16x8 (&A)[NG], const bf16x8 (&bv)[NJW])
        __attribute__((always_inline)) {
#pragma unroll
        for (int j2 = 0; j2 < NJW; ++j2)
#pragma unroll
            for (int g = 0; g < NG; ++g)
                acc[g * NJW + j2] = __builtin_amdgcn_mfma_f32_16x16x32_bf16(A[g], bv[j2], acc[g * NJW + j2], 0, 0, 0);
    };

#pragma unroll 1
    for (int rep = 0; rep < REP; ++rep) {
#pragma unroll
        for (int i = 0; i < NG * NJW; ++i) acc[i] = (f32x4){0.f, 0.f, 0.f, 0.f};

        // prologue: 4 steps in flight
        LOADA(0, 0);      LOADB(0, 0);
        LOADA(1, KT);     LOADB(1, KT);
        LOADA(2, 2 * KT); LOADB(2, 2 * KT);
        LOADA(3, 3 * KT); LOADB(3, 3 * KT);

#pragma unroll 1
        for (int s = 0; s < SW - 4; s += 4) {
            { MKFRAGS(0, A0); mfma_all(A0, bq0); LOADA(0, (s + 4) * KT); LOADB(0, (s + 4) * KT); }
            { MKFRAGS(1, A1); mfma_all(A1, bq1); LOADA(1, (s + 5) * KT); LOADB(1, (s + 5) * KT); }
            { MKFRAGS(2, A2); mfma_all(A2, bq2); LOADA(2, (s + 6) * KT); LOADB(2, (s + 6) * KT); }
            { MKFRAGS(3, A3); mfma_all(A3, bq3); LOADA(3, (s + 7) * KT); LOADB(3, (s + 7) * KT); }
        }
        // drain: consume steps SW-4..SW-1
        { MKFRAGS(0, A0); mfma_all(A0, bq0); }
        { MKFRAGS(1, A1); mfma_all(A1, bq1); }
        { MKFRAGS(2, A2); mfma_all(A2, bq2); }
        { MKFRAGS(3, A3); mfma_all(A3, bq3); }

        // ---- per-wave epilogue (disjoint slices; no reduction, no barrier) ----
        float mul[NG][4];
        if constexpr (MODE != 0) {
#pragma unroll
            for (int g = 0; g < NG; ++g) {
                const float4 rv = *(const float4*)&rcp[(size_t)batch * RL + m0 + g * 16 + quad * 4];
                mul[g][0] = rv.x; mul[g][1] = rv.y; mul[g][2] = rv.z; mul[g][3] = rv.w;
            }
        }
#pragma unroll
        for (int g = 0; g < NG; ++g) {
            const int row = m0 + g * 16 + quad * 4;
            if constexpr (MODE == 2) {
                float* op = outF + ((size_t)batch * N_ + row) * C_;
#pragma unroll
                for (int j2 = 0; j2 < NJW; ++j2) {
                    const int c = (jw + j2) * 16 + l15;
#pragma unroll
                    for (int r = 0; r < 4; ++r) op[(size_t)r * C_ + c] = acc[g * NJW + j2][r] * mul[g][r];
                }
            } else {
#pragma unroll
                for (int j2 = 0; j2 < NJW; ++j2) {
                    const int c = (jw + j2) * 16 + l15;
                    float v0, v1, v2, v3;
                    if constexpr (MODE == 0) {
                        float bb = bias[c];
                        v0 = acc[g * NJW + j2][0] + bb; v1 = acc[g * NJW + j2][1] + bb;
                        v2 = acc[g * NJW + j2][2] + bb; v3 = acc[g * NJW + j2][3] + bb;
                    } else {
                        v0 = acc[g * NJW + j2][0] * mul[g][0]; v1 = acc[g * NJW + j2][1] * mul[g][1];
                        v2 = acc[g * NJW + j2][2] * mul[g][2]; v3 = acc[g * NJW + j2][3] * mul[g][3];
                    }
                    uint32_t q0 = (uint32_t)bf16_rne(v0) | ((uint32_t)bf16_rne(v1) << 16);
                    uint32_t q1 = (uint32_t)bf16_rne(v2) | ((uint32_t)bf16_rne(v3) << 16);
                    uint16_t* op = outT + ((size_t)batch * C_ + c) * OLD + row;
                    *(uint2*)op = make_uint2(q0, q1);
                }
            }
        }
    }
}

// Named wrappers -> attributable rocprof rows
__global__ __launch_bounds__(256, 2)
void fc_k(const float* __restrict__ Ax, const uint16_t* __restrict__ Btb,
          const float* __restrict__ bias, uint16_t* __restrict__ outT) {
    gemm_body<0, 1>(Ax, nullptr, Btb, bias, nullptr, outT, nullptr);
}
__global__ __launch_bounds__(256, 2)
void v2e_k(const uint32_t* __restrict__ HT, const uint16_t* __restrict__ Btb,
           const float* __restrict__ rcp, uint16_t* __restrict__ outT) {
    gemm_body<1, 1>(nullptr, HT, Btb, nullptr, rcp, outT, nullptr);
}
__global__ __launch_bounds__(256, 2)
void e2v_k(const uint32_t* __restrict__ HT, const uint16_t* __restrict__ Btb,
           const float* __restrict__ rcp, float* __restrict__ outF) {
    gemm_body<2, 1>(nullptr, HT, Btb, nullptr, rcp, nullptr, outF);
}

// ---------------------------------------------------------------------------
extern "C" void kernel_launch(void* const* d_in, const int* in_sizes, int n_in,
                              void* d_out, int out_size, void* d_ws, size_t ws_size,
                              hipStream_t stream) {
    const float* x    = (const float*)d_in[0];   // [8,4096,128]
    const float* H    = (const float*)d_in[1];   // [8,4096,2048]
    const float* W    = (const float*)d_in[2];   // [128,128]
    const float* bias = (const float*)d_in[3];   // [128]
    float* out = (float*)d_out;                  // [8,4096,128]

    // ws (~12.3 MB): HT 8MB | WTb 32KB | ebfT 4MB | rs_e 64KB | rd_n 128KB
    uint32_t* HT   = (uint32_t*)d_ws;
    uint16_t* WTb  = (uint16_t*)(HT + HT_E);
    uint16_t* ebfT = WTb + WT_E;
    float*    rs_e = (float*)(ebfT + EBF_E);
    float*    rd_n = rs_e + RS_E;
    uint16_t* xwbT = (uint16_t*)d_out;           // d_out is dead scratch until e2v

    pack_kernel<<<dim3(8192), dim3(256), 0, stream>>>(H, HT);
    prep_kernel<<<dim3(384), dim3(256), 0, stream>>>(W, HT, WTb, rs_e, rd_n);
    fc_k <<<dim3(8 * (N_ / MT)), dim3(256), 0, stream>>>(x, WTb, bias, xwbT);
    v2e_k<<<dim3(8 * (E_ / MT)), dim3(256), 0, stream>>>(HT, xwbT, rs_e, ebfT);
    e2v_k<<<dim3(8 * (N_ / MT)), dim3(256), 0, stream>>>(HT, ebfT, rd_n, out);
}